// Round 7
// baseline (2363.916 us; speedup 1.0000x reference)
//
#include <hip/hip_runtime.h>
#include <hip/hip_bf16.h>

#define N_NODES 50000
#define N_EDGES 600000
#define CH 128
#define N_LAYERS 15
#define GB 782                      // gemm grid: 64-row tiles

typedef float f32x4 __attribute__((ext_vector_type(4)));
typedef short s16x8 __attribute__((ext_vector_type(8)));
typedef unsigned short u16x4 __attribute__((ext_vector_type(4)));

#define LD8(p) (*(const s16x8*)(p))

__device__ __forceinline__ float eluf(float v) {
    return v > 0.f ? v : (__expf(v) - 1.f);
}
__device__ __forceinline__ unsigned short f2bf(float f) {
    unsigned int u = __float_as_uint(f);
    unsigned int r = (u + 0x7FFFu + ((u >> 16) & 1u)) >> 16;
    return (unsigned short)r;
}
__device__ __forceinline__ float bf2f(unsigned short h) {
    return __uint_as_float(((unsigned int)h) << 16);
}
__device__ __forceinline__ void gload_lds16(const unsigned short* g, unsigned short* l) {
    __builtin_amdgcn_global_load_lds(
        (const __attribute__((address_space(1))) unsigned int*)g,
        (__attribute__((address_space(3))) unsigned int*)l, 16, 0, 0);
}

// ---------------- conv1 ----------------
__global__ __launch_bounds__(256) void conv1_kernel(
    const float* __restrict__ in, const float* __restrict__ W1,
    const float* __restrict__ b1, float* __restrict__ x,
    unsigned short* __restrict__ hbh, unsigned short* __restrict__ hbl, int n)
{
    int idx = blockIdx.x * blockDim.x + threadIdx.x;
    if (idx >= n * CH) return;
    int node = idx >> 7;
    int c = idx & 127;
    float o = b1[c]
            + in[(size_t)node * 3 + 0] * W1[0 * CH + c]
            + in[(size_t)node * 3 + 1] * W1[1 * CH + c]
            + in[(size_t)node * 3 + 2] * W1[2 * CH + c];
    x[idx] = o;
    float e = eluf(o);
    unsigned short hi = f2bf(e);
    hbh[idx] = hi;
    hbl[idx] = f2bf(e - bf2f(hi));
}

// ---------------- zero helpers ----------------
__global__ __launch_bounds__(256) void zero_int_kernel(int* __restrict__ p, int n) {
    int i = blockIdx.x * blockDim.x + threadIdx.x;
    if (i < n) p[i] = 0;
}
__global__ __launch_bounds__(256) void zero_float_kernel(float* __restrict__ p, int n) {
    int i = blockIdx.x * blockDim.x + threadIdx.x;
    if (i < n) p[i] = 0.f;
}

// ---------------- CSR build ----------------
__global__ __launch_bounds__(256) void count_kernel(
    const int* __restrict__ row, int* __restrict__ cnt, int e)
{
    int i = blockIdx.x * blockDim.x + threadIdx.x;
    if (i < e) atomicAdd(&cnt[row[i]], 1);
}

__global__ __launch_bounds__(1024) void block_reduce_kernel(
    const int* __restrict__ cnt, int* __restrict__ bsum, int n)
{
    __shared__ int sd[1024];
    int tid = threadIdx.x;
    int i = blockIdx.x * 1024 + tid;
    sd[tid] = (i < n) ? cnt[i] : 0;
    __syncthreads();
    for (int off = 512; off > 0; off >>= 1) {
        if (tid < off) sd[tid] += sd[tid + off];
        __syncthreads();
    }
    if (tid == 0) bsum[blockIdx.x] = sd[0];
}

__global__ __launch_bounds__(64) void scan_small_kernel(
    const int* __restrict__ bsum, int* __restrict__ boff, int nb)
{
    int lane = threadIdx.x;
    int orig = (lane < nb) ? bsum[lane] : 0;
    int v = orig;
#pragma unroll
    for (int d = 1; d < 64; d <<= 1) {
        int t = __shfl_up(v, d, 64);
        if (lane >= d) v += t;
    }
    if (lane < nb) boff[lane] = v - orig;  // exclusive
}

__global__ __launch_bounds__(1024) void block_scan_kernel(
    const int* __restrict__ cnt, const int* __restrict__ boff,
    int* __restrict__ row_ptr, int n)
{
    __shared__ int sd[1024];
    int tid = threadIdx.x;
    int i = blockIdx.x * 1024 + tid;
    sd[tid] = (i < n) ? cnt[i] : 0;
    __syncthreads();
    for (int off = 1; off < 1024; off <<= 1) {
        int t = (tid >= off) ? sd[tid - off] : 0;
        __syncthreads();
        sd[tid] += t;
        __syncthreads();
    }
    if (i < n) row_ptr[i + 1] = sd[tid] + boff[blockIdx.x];
    if (i == 0) row_ptr[0] = 0;
}

// col_s stores byte offset of the gather row start: col << 8
__global__ __launch_bounds__(256) void fill_kernel(
    const int* __restrict__ row, const int* __restrict__ col,
    const float* __restrict__ val, int* __restrict__ cursor,
    const int* __restrict__ row_ptr, int* __restrict__ col_s,
    float* __restrict__ val_s, int e)
{
    int i = blockIdx.x * blockDim.x + threadIdx.x;
    if (i >= e) return;
    int r = row[i];
    int pos = atomicAdd(&cursor[r], 1);
    int dst = row_ptr[r] + pos;
    col_s[dst] = col[i] << 8;
    val_s[dst] = val[i];
}

// ---------------- mask denominator ----------------
__global__ __launch_bounds__(256) void mask_sum_kernel(
    const float* __restrict__ mask, float* __restrict__ denom, int n)
{
    __shared__ float sd[256];
    int tid = threadIdx.x;
    float s = 0.f;
    for (int i = blockIdx.x * 256 + tid; i < n; i += gridDim.x * 256) s += mask[i];
    sd[tid] = s;
    __syncthreads();
    for (int off = 128; off > 0; off >>= 1) {
        if (tid < off) sd[tid] += sd[tid + off];
        __syncthreads();
    }
    if (tid == 0) atomicAdd(denom, sd[0]);
}

// ---- W pre-split into MFMA-fragment order (hi + lo planes) ----
__global__ __launch_bounds__(256) void split_w_kernel(
    const float* __restrict__ W, unsigned short* __restrict__ Wf, int total)
{
    int id = blockIdx.x * 256 + threadIdx.x;
    if (id >= total) return;
    int s = id >> 15;
    int rem = id & 32767;
    int k = rem >> 7;
    int nn = rem & 127;
    float a = W[id];
    unsigned short hi = f2bf(a);
    float r = a - bf2f(hi);
    unsigned short mi = f2bf(r);
    int c   = k >> 5;
    int kin = k & 31;
    int q   = kin >> 3;
    int ko  = kin & 7;
    int nt  = nn >> 4;
    int c16 = nn & 15;
    int lane = q * 16 + c16;
    size_t base = (size_t)s * 65536 + (size_t)c * 4096 + (size_t)nt * 512
                + (size_t)lane * 8 + ko;
    Wf[base]         = hi;
    Wf[base + 32768] = mi;
}

// ======== shared GEMM building blocks ========
// LDS convention (both kernels): region holds 64 rows x 256B; within a row,
// 16B slot s holds global channel-slot s ^ (row&7)  (bank-conflict swizzle,
// applied on BOTH producer addr and consumer ds_read — rule 21).

__device__ __forceinline__ void dense4(
    const unsigned short* r0, const unsigned short* r1,
    const unsigned short* wf0, f32x4 (&acc)[2][4],
    s16x8 (&b0)[4], s16x8 (&b1)[4],
    int lrA, int lrB, int q, int xr, bool pf_last)
{
#pragma unroll
    for (int ch = 0; ch < 4; ++ch) {
        s16x8 nb0[4], nb1[4];
        const bool pf = (ch < 3) || pf_last;
        if (pf) {
            const unsigned short* nwp = wf0 + (size_t)(ch + 1) * 4096;
#pragma unroll
            for (int nt = 0; nt < 4; ++nt) {
                nb0[nt] = LD8(nwp + nt * 512);
                nb1[nt] = LD8(nwp + nt * 512 + 32768);
            }
        }
        const int sl = (((ch * 4 + q) ^ xr) << 3);
        s16x8 aH0 = LD8(r0 + lrA * 128 + sl);
        s16x8 aH1 = LD8(r0 + lrB * 128 + sl);
        s16x8 aL0 = LD8(r1 + lrA * 128 + sl);
        s16x8 aL1 = LD8(r1 + lrB * 128 + sl);
#pragma unroll
        for (int nt = 0; nt < 4; ++nt) {
            f32x4 c0 = acc[0][nt];
            c0 = __builtin_amdgcn_mfma_f32_16x16x32_bf16(aH0, b0[nt], c0, 0, 0, 0);
            c0 = __builtin_amdgcn_mfma_f32_16x16x32_bf16(aH0, b1[nt], c0, 0, 0, 0);
            c0 = __builtin_amdgcn_mfma_f32_16x16x32_bf16(aL0, b0[nt], c0, 0, 0, 0);
            acc[0][nt] = c0;
            f32x4 c1 = acc[1][nt];
            c1 = __builtin_amdgcn_mfma_f32_16x16x32_bf16(aH1, b0[nt], c1, 0, 0, 0);
            c1 = __builtin_amdgcn_mfma_f32_16x16x32_bf16(aH1, b1[nt], c1, 0, 0, 0);
            c1 = __builtin_amdgcn_mfma_f32_16x16x32_bf16(aL1, b0[nt], c1, 0, 0, 0);
            acc[1][nt] = c1;
        }
        if (pf) {
#pragma unroll
            for (int nt = 0; nt < 4; ++nt) { b0[nt] = nb0[nt]; b1[nt] = nb1[nt]; }
        }
    }
}

__device__ __forceinline__ void prop4(
    const unsigned short* r1, const unsigned short* wf0, f32x4 (&acc)[2][4],
    s16x8 (&b0)[4], s16x8 (&b1)[4], int lrA, int lrB, int q, int xr)
{
#pragma unroll
    for (int cc = 0; cc < 4; ++cc) {
        s16x8 nb0[4], nb1[4];
        if (cc < 3) {
            const unsigned short* nwp = wf0 + (size_t)(5 + cc) * 4096;
#pragma unroll
            for (int nt = 0; nt < 4; ++nt) {
                nb0[nt] = LD8(nwp + nt * 512);
                nb1[nt] = LD8(nwp + nt * 512 + 32768);
            }
        }
        const int sl = (((cc * 4 + q) ^ xr) << 3);
        s16x8 p0 = LD8(r1 + lrA * 128 + sl);
        s16x8 p1 = LD8(r1 + lrB * 128 + sl);
#pragma unroll
        for (int nt = 0; nt < 4; ++nt) {
            f32x4 c0 = acc[0][nt];
            c0 = __builtin_amdgcn_mfma_f32_16x16x32_bf16(p0, b0[nt], c0, 0, 0, 0);
            c0 = __builtin_amdgcn_mfma_f32_16x16x32_bf16(p0, b1[nt], c0, 0, 0, 0);
            acc[0][nt] = c0;
            f32x4 c1 = acc[1][nt];
            c1 = __builtin_amdgcn_mfma_f32_16x16x32_bf16(p1, b0[nt], c1, 0, 0, 0);
            c1 = __builtin_amdgcn_mfma_f32_16x16x32_bf16(p1, b1[nt], c1, 0, 0, 0);
            acc[1][nt] = c1;
        }
        if (cc < 3) {
#pragma unroll
            for (int nt = 0; nt < 4; ++nt) { b0[nt] = nb0[nt]; b1[nt] = nb1[nt]; }
        }
    }
}

__device__ __forceinline__ void tile_phase1(
    float* tile, const f32x4 (&acc)[2][4], const float* bias_s,
    int wm, int wn, int q, int c16)
{
#pragma unroll
    for (int mt = 0; mt < 2; ++mt)
#pragma unroll
        for (int nt = 0; nt < 4; ++nt) {
            int col = wn * 64 + nt * 16 + c16;
            float bv = bias_s[col];
            int lrow = wm * 32 + mt * 16 + q * 4;
#pragma unroll
            for (int r = 0; r < 4; ++r)
                tile[(lrow + r) * 132 + col] = acc[mt][nt][r] + bv;
        }
}

__device__ __forceinline__ void flush_tile(
    const float* tile, int m_base, int tid, int n,
    const float* res, float* out,
    unsigned short* Oh, unsigned short* Ol,
    const float* mask, float* csum, bool do_acc)
{
    float colsum[4] = {0.f, 0.f, 0.f, 0.f};
    const int c4 = (tid & 31) << 2;
    for (int e4 = tid; e4 < 2048; e4 += 256) {
        int row = e4 >> 5;
        int grow = m_base + row;
        if (grow < n) {
            f32x4 v = *(const f32x4*)&tile[row * 132 + c4];
            size_t o4 = (size_t)grow * CH + c4;
            if (res) v = v + *(const f32x4*)(res + o4);
            if (out) *(f32x4*)(out + o4) = v;
            float e0 = eluf(v[0]), e1 = eluf(v[1]), e2 = eluf(v[2]), e3 = eluf(v[3]);
            unsigned short h0 = f2bf(e0), h1 = f2bf(e1), h2 = f2bf(e2), h3 = f2bf(e3);
            u16x4 hv = {h0, h1, h2, h3};
            u16x4 lv = {f2bf(e0 - bf2f(h0)), f2bf(e1 - bf2f(h1)),
                        f2bf(e2 - bf2f(h2)), f2bf(e3 - bf2f(h3))};
            *(u16x4*)(Oh + o4) = hv;
            *(u16x4*)(Ol + o4) = lv;
            if (do_acc) {
                float mk = mask[grow];
                colsum[0] += mk * e0; colsum[1] += mk * e1;
                colsum[2] += mk * e2; colsum[3] += mk * e3;
            }
        }
    }
    if (do_acc) {
#pragma unroll
        for (int jj = 0; jj < 4; ++jj) atomicAdd(&csum[c4 + jj], colsum[jj]);
    }
}

// ---------------- LAP GEMM: R5-validated gemm + IN-KERNEL Laplacian gather.
// Gather input (Ah, all rows) comes from the PREVIOUS DISPATCH -> visibility
// by dispatch boundary (no fences needed). Prop plane never touches global:
// gathered straight into LDS r1 (overwriting the consumed lo plane).
__global__ __launch_bounds__(256, 4) void gemm_lap_kernel(
    const unsigned short* __restrict__ Ah, const unsigned short* __restrict__ Al,
    const unsigned short* __restrict__ Wf, const float* __restrict__ bias,
    const float* __restrict__ res, float* __restrict__ out,
    unsigned short* __restrict__ Oh, unsigned short* __restrict__ Ol,
    const float* __restrict__ mask, float* __restrict__ accp,
    const int* __restrict__ rp, const int* __restrict__ cols,
    const float* __restrict__ vals, int n)
{
    __shared__ __align__(16) char smem[33792];
    __shared__ float csum[128];
    __shared__ float bias_s[128];
    unsigned short* r0 = (unsigned short*)smem;
    unsigned short* r1 = (unsigned short*)(smem + 16896);
    float* tile = (float*)smem;

    const int tid = threadIdx.x;
    const int m_base = blockIdx.x * 64;
    const int wid = tid >> 6, lane = tid & 63;
    const int wm = wid & 1, wn = wid >> 1;
    const int q = lane >> 4, c16 = lane & 15;
    const int lrA = wm * 32 + c16, lrB = lrA + 16;
    const int xr = lrA & 7;

    // stage hi->r0, lo->r1 (swizzled source, linear LDS dest)
    {
        const int lr = tid >> 4, slot = tid & 15;
#pragma unroll
        for (int k = 0; k < 4; ++k) {
            int row = k * 16 + lr;
            int ss = (slot ^ (row & 7)) * 8;
            size_t g = (size_t)(m_base + row) * CH + ss;
            gload_lds16(Ah + g, r0 + k * 2048 + tid * 8);
            gload_lds16(Al + g, r1 + k * 2048 + tid * 8);
        }
    }
    if (tid < 128) bias_s[tid] = bias[tid];

    f32x4 acc[2][4];
#pragma unroll
    for (int a = 0; a < 2; a++)
#pragma unroll
        for (int b = 0; b < 4; b++) acc[a][b] = (f32x4){0.f, 0.f, 0.f, 0.f};

    const unsigned short* wf0 = Wf + wn * 2048 + lane * 8;
    s16x8 b0[4], b1[4];
#pragma unroll
    for (int nt = 0; nt < 4; ++nt) {
        b0[nt] = LD8(wf0 + nt * 512);
        b1[nt] = LD8(wf0 + nt * 512 + 32768);
    }
    __syncthreads();                      // staging drained; bias_s visible

    dense4(r0, r1, wf0, acc, b0, b1, lrA, lrB, q, xr, true);

    __syncthreads();                      // lo reads done -> r1 reusable
    // ---- in-kernel gather: own 64 rows over ALL-rows Ah -> r1 (prop) ----
    {
        const char* hbase = (const char*)Ah;
        const int gw = tid >> 6, gl = tid & 63;
        for (int rr = 0; rr < 16; ++rr) {
            int lrow = gw * 16 + rr;
            int grow = m_base + lrow;
            float a0 = 0.f, a1 = 0.f;
            if (grow < n) {
                int st = rp[grow], en = rp[grow + 1];
                int t = st;
                for (; t + 4 <= en; t += 4) {
                    int e0 = cols[t], e1 = cols[t + 1];
                    int e2 = cols[t + 2], e3 = cols[t + 3];
                    float v0 = vals[t], v1 = vals[t + 1];
                    float v2 = vals[t + 2], v3 = vals[t + 3];
                    unsigned int u0 = *(const unsigned int*)(hbase + e0 + gl * 4);
                    unsigned int u1 = *(const unsigned int*)(hbase + e1 + gl * 4);
                    unsigned int u2 = *(const unsigned int*)(hbase + e2 + gl * 4);
                    unsigned int u3 = *(const unsigned int*)(hbase + e3 + gl * 4);
                    a0 += v0 * bf2f((unsigned short)u0) + v1 * bf2f((unsigned short)u1)
                        + v2 * bf2f((unsigned short)u2) + v3 * bf2f((unsigned short)u3);
                    a1 += v0 * bf2f((unsigned short)(u0 >> 16)) + v1 * bf2f((unsigned short)(u1 >> 16))
                        + v2 * bf2f((unsigned short)(u2 >> 16)) + v3 * bf2f((unsigned short)(u3 >> 16));
                }
                for (; t < en; ++t) {
                    unsigned int u = *(const unsigned int*)(hbase + cols[t] + gl * 4);
                    float v = vals[t];
                    a0 += v * bf2f((unsigned short)u);
                    a1 += v * bf2f((unsigned short)(u >> 16));
                }
            }
            int sw = (gl >> 2) ^ (lrow & 7);
            *(unsigned int*)((char*)r1 + lrow * 256 + sw * 16 + (gl & 3) * 4)
                = (unsigned int)f2bf(a0) | ((unsigned int)f2bf(a1) << 16);
        }
    }
    __syncthreads();                      // prop plane ready

    prop4(r1, wf0, acc, b0, b1, lrA, lrB, q, xr);

    // ---- epilogue (tile overlays r0+r1) ----
    if (accp && tid < 128) csum[tid] = 0.f;
    __syncthreads();
    tile_phase1(tile, acc, bias_s, wm, wn, q, c16);
    __syncthreads();
    flush_tile(tile, m_base, tid, n, res, out, Oh, Ol, mask, csum, accp != nullptr);
    if (accp) {
        __syncthreads();
        if (tid < 128) atomicAdd(&accp[tid], csum[tid]);
    }
}

// ---------------- AVG layer, BOTH inner steps fused in one dispatch.
// j0 output planes live ONLY in LDS (no global traffic); the 128-float
// column-sum crosses blocks via device-scope atomics (add-side and load-side)
// guarded by a done-counter spin. 782 blocks <= 1024 capacity at 4 blk/CU
// (LDS 36.4KB, launch_bounds(256,4)) -> all co-resident, spin is safe.
__global__ __launch_bounds__(256, 4) void gemm_avg_kernel(
    const unsigned short* Ah, const unsigned short* Al,   // in planes (alias out)
    unsigned short* Oh, unsigned short* Ol,
    const unsigned short* __restrict__ Wf0, const unsigned short* __restrict__ Wf1,
    const float* __restrict__ bias0, const float* __restrict__ bias1,
    const float* __restrict__ Wb0, const float* __restrict__ Wb1,
    const float* __restrict__ accv0, float* __restrict__ accm,
    int* __restrict__ done,
    const float* __restrict__ res, float* __restrict__ out,
    const float* __restrict__ mask, const float* __restrict__ denom, int n)
{
    __shared__ __align__(16) char smem[33792];
    __shared__ float csum[128];
    __shared__ float partial[256];
    __shared__ float bias_s[128];
    __shared__ float avg_s[128];
    unsigned short* r0 = (unsigned short*)smem;
    unsigned short* r1 = (unsigned short*)(smem + 16896);
    float* tile = (float*)smem;

    const int tid = threadIdx.x;
    const int m_base = blockIdx.x * 64;
    const int wid = tid >> 6, lane = tid & 63;
    const int wm = wid & 1, wn = wid >> 1;
    const int q = lane >> 4, c16 = lane & 15;
    const int lrA = wm * 32 + c16, lrB = lrA + 16;
    const int xr = lrA & 7;

    // ======== step j0 ========
    {
        const int lr = tid >> 4, slot = tid & 15;
#pragma unroll
        for (int k = 0; k < 4; ++k) {
            int row = k * 16 + lr;
            int ss = (slot ^ (row & 7)) * 8;
            size_t g = (size_t)(m_base + row) * CH + ss;
            gload_lds16(Ah + g, r0 + k * 2048 + tid * 8);
            gload_lds16(Al + g, r1 + k * 2048 + tid * 8);
        }
    }
    if (tid < 128) bias_s[tid] = bias0[tid];
    {   // bias2 GEMV from prev-dispatch acc slot (normal loads OK: boundary)
        float rden = 1.f / denom[0];
        int c = tid & 127, h = tid >> 7;
        float o = 0.f;
#pragma unroll 8
        for (int k = h * 64; k < h * 64 + 64; ++k) o += accv0[k] * Wb0[(size_t)k * CH + c];
        partial[tid] = o * rden;
    }
    f32x4 acc[2][4];
#pragma unroll
    for (int a = 0; a < 2; a++)
#pragma unroll
        for (int b = 0; b < 4; b++) acc[a][b] = (f32x4){0.f, 0.f, 0.f, 0.f};

    const unsigned short* w0 = Wf0 + wn * 2048 + lane * 8;
    s16x8 b0[4], b1[4];
#pragma unroll
    for (int nt = 0; nt < 4; ++nt) {
        b0[nt] = LD8(w0 + nt * 512);
        b1[nt] = LD8(w0 + nt * 512 + 32768);
    }
    __syncthreads();
    if (tid < 128) bias_s[tid] += partial[tid] + partial[tid + 128];

    dense4(r0, r1, w0, acc, b0, b1, lrA, lrB, q, xr, false);

    // ---- epilogue-0: elu planes -> LDS r0/r1 (swizzled) + column-sum ----
    if (tid < 128) csum[tid] = 0.f;
    __syncthreads();                      // frag reads done -> overwrite safe
    {
        float colsum[4] = {0.f, 0.f, 0.f, 0.f};
#pragma unroll
        for (int mt = 0; mt < 2; ++mt)
#pragma unroll
            for (int nt = 0; nt < 4; ++nt) {
                int col = wn * 64 + nt * 16 + c16;
                float bv = bias_s[col];
                int cs = col >> 3, ci = col & 7;
#pragma unroll
                for (int r = 0; r < 4; ++r) {
                    int lrow = wm * 32 + mt * 16 + q * 4 + r;
                    float o = acc[mt][nt][r] + bv;
                    float e = eluf(o);
                    unsigned short hi = f2bf(e);
                    unsigned short lo = f2bf(e - bf2f(hi));
                    int off = lrow * 128 + ((cs ^ (lrow & 7)) << 3) + ci;
                    r0[off] = hi;
                    r1[off] = lo;
                    int grow = m_base + lrow;
                    if (grow < n) colsum[nt] += mask[grow] * e;
                }
            }
#pragma unroll
        for (int nt = 0; nt < 4; ++nt)
            atomicAdd(&csum[wn * 64 + nt * 16 + c16], colsum[nt]);
    }
    __syncthreads();
    if (tid < 128) atomicAdd(&accm[tid], csum[tid]);
    __syncthreads();                      // all acc atomics drained (per-thread vmcnt)
    if (tid == 0) {
        __threadfence();
        __hip_atomic_fetch_add(done, 1, __ATOMIC_RELEASE, __HIP_MEMORY_SCOPE_AGENT);
        while (__hip_atomic_load(done, __ATOMIC_RELAXED, __HIP_MEMORY_SCOPE_AGENT) < GB)
            __builtin_amdgcn_s_sleep(2);
        __threadfence();
    }
    __syncthreads();

    // ======== step j1 ========
    if (tid < 128) {
        bias_s[tid] = bias1[tid];
        avg_s[tid] = __hip_atomic_load(accm + tid, __ATOMIC_RELAXED,
                                       __HIP_MEMORY_SCOPE_AGENT) / denom[0];
    }
    __syncthreads();
    {
        int c = tid & 127, h = tid >> 7;
        float o = 0.f;
#pragma unroll 8
        for (int k = h * 64; k < h * 64 + 64; ++k) o += avg_s[k] * Wb1[(size_t)k * CH + c];
        partial[tid] = o;
    }
    const unsigned short* w1 = Wf1 + wn * 2048 + lane * 8;
#pragma unroll
    for (int nt = 0; nt < 4; ++nt) {
        b0[nt] = LD8(w1 + nt * 512);
        b1[nt] = LD8(w1 + nt * 512 + 32768);
    }
#pragma unroll
    for (int a = 0; a < 2; a++)
#pragma unroll
        for (int b = 0; b < 4; b++) acc[a][b] = (f32x4){0.f, 0.f, 0.f, 0.f};
    __syncthreads();
    if (tid < 128) bias_s[tid] += partial[tid] + partial[tid + 128];

    dense4(r0, r1, w1, acc, b0, b1, lrA, lrB, q, xr, false);

    // ---- epilogue-1: coalesced global flush ----
    __syncthreads();                      // frag reads done; bias_s final
    tile_phase1(tile, acc, bias_s, wm, wn, q, c16);
    __syncthreads();
    flush_tile(tile, m_base, tid, n, res, out, Oh, Ol, mask, csum, false);
}

// ---------------- final head ----------------
__global__ __launch_bounds__(256) void final_kernel(
    const unsigned short* __restrict__ hh, const unsigned short* __restrict__ hl,
    const float* __restrict__ W2, const float* __restrict__ b2,
    const float* __restrict__ in, float* __restrict__ out, int n)
{
    int wave = (blockIdx.x * blockDim.x + threadIdx.x) >> 6;
    int lane = threadIdx.x & 63;
    int stride = gridDim.x * 4;
    for (int row = wave; row < n; row += stride) {
        size_t i1 = (size_t)row * CH + lane;
        size_t i2 = i1 + 64;
        float v = (bf2f(hh[i1]) + bf2f(hl[i1])) * W2[lane]
                + (bf2f(hh[i2]) + bf2f(hl[i2])) * W2[64 + lane];
#pragma unroll
        for (int off = 32; off > 0; off >>= 1) v += __shfl_down(v, off, 64);
        if (lane == 0) out[row] = v + b2[0] + in[(size_t)row * 3];
    }
}

extern "C" void kernel_launch(void* const* d_in, const int* in_sizes, int n_in,
                              void* d_out, int out_size, void* d_ws, size_t ws_size,
                              hipStream_t stream)
{
    const int*   L_row   = (const int*)d_in[0];
    const int*   L_col   = (const int*)d_in[1];
    const float* L_val   = (const float*)d_in[2];
    const float* mask    = (const float*)d_in[3];
    const float* inputs  = (const float*)d_in[4];
    const float* conv1_W = (const float*)d_in[5];
    const float* conv1_b = (const float*)d_in[6];
    const float* blocks_W = (const float*)d_in[7];
    const float* blocks_b = (const float*)d_in[8];
    const float* conv2_W = (const float*)d_in[9];
    const float* conv2_b = (const float*)d_in[10];
    float* out = (float*)d_out;

    const int N = N_NODES, E = N_EDGES;
    const size_t NF = (size_t)N * CH;
    const int NPAD = 50048;
    const int NB = (N + 1023) / 1024;

    float* ws = (float*)d_ws;
    float* x0 = ws;
    float* x1 = x0 + NF;
    unsigned short* hbh0 = (unsigned short*)(x1 + NF);
    unsigned short* hbl0 = hbh0 + NF;
    unsigned short* hbh1 = hbl0 + NF;
    unsigned short* hbl1 = hbh1 + NF;
    unsigned short* ph   = hbl1 + NF;                   // unused; keeps layout
    int* cnt     = (int*)(ph + 2 * NF);
    int* cursor  = cnt + NPAD;
    int* row_ptr = cursor + NPAD;
    int* bsum    = row_ptr + NPAD;
    int* boff    = bsum + 64;
    int* col_s   = boff + 64;
    float* val_s = (float*)(col_s + E);
    float* acc_base = val_s + E;                        // 14 slots x 128
    float* denom    = acc_base + 14 * CH;
    int* done_base  = (int*)(denom + 8);                // 7 counters (zeroed)
    unsigned short* wt = (unsigned short*)(denom + 16 + 160);

    zero_int_kernel<<<(2 * NPAD + 255) / 256, 256, 0, stream>>>(cnt, 2 * NPAD);
    zero_float_kernel<<<(14 * CH + 16 + 255) / 256, 256, 0, stream>>>(acc_base, 14 * CH + 16);
    count_kernel<<<(E + 255) / 256, 256, 0, stream>>>(L_row, cnt, E);
    block_reduce_kernel<<<NB, 1024, 0, stream>>>(cnt, bsum, N);
    scan_small_kernel<<<1, 64, 0, stream>>>(bsum, boff, NB);
    block_scan_kernel<<<NB, 1024, 0, stream>>>(cnt, boff, row_ptr, N);
    fill_kernel<<<(E + 255) / 256, 256, 0, stream>>>(L_row, L_col, L_val, cursor,
                                                     row_ptr, col_s, val_s, E);
    mask_sum_kernel<<<64, 256, 0, stream>>>(mask, denom, N);
    split_w_kernel<<<(30 * 32768 + 255) / 256, 256, 0, stream>>>(blocks_W, wt, 30 * 32768);

    conv1_kernel<<<(N * CH + 255) / 256, 256, 0, stream>>>(inputs, conv1_W, conv1_b,
                                                           x0, hbh0, hbl0, N);

    float* xin = x0;
    float* xout = x1;

    for (int i = 0; i < N_LAYERS; ++i) {
        if ((i & 1) == 0) {
            // lap layer: two dispatches, gather fused into each gemm
            int s0 = i * 2, s1 = s0 + 1;
            gemm_lap_kernel<<<GB, 256, 0, stream>>>(
                hbh0, hbl0, wt + (size_t)s0 * 65536, blocks_b + (size_t)s0 * CH,
                nullptr, nullptr, hbh1, hbl1, mask, nullptr,
                row_ptr, col_s, val_s, N);
            float* accp1 = (i < 14) ? acc_base + (size_t)i * CH : nullptr;
            gemm_lap_kernel<<<GB, 256, 0, stream>>>(
                hbh1, hbl1, wt + (size_t)s1 * 65536, blocks_b + (size_t)s1 * CH,
                xin, xout, hbh0, hbl0, mask, accp1,
                row_ptr, col_s, val_s, N);
        } else {
            // avg layer: ONE fused dispatch (j0 planes in LDS, acc via atomics)
            int s0 = i * 2, s1 = s0 + 1;
            gemm_avg_kernel<<<GB, 256, 0, stream>>>(
                hbh0, hbl0, hbh0, hbl0,
                wt + (size_t)s0 * 65536, wt + (size_t)s1 * 65536,
                blocks_b + (size_t)s0 * CH, blocks_b + (size_t)s1 * CH,
                blocks_W + (size_t)s0 * 256 * CH + 128 * CH,
                blocks_W + (size_t)s1 * 256 * CH + 128 * CH,
                acc_base + (size_t)(i - 1) * CH, acc_base + (size_t)i * CH,
                done_base + (i >> 1),
                xin, xout, mask, denom, N);
        }
        float* t = xin; xin = xout; xout = t;
    }
    final_kernel<<<2048, 256, 0, stream>>>(hbh0, hbl0, conv2_W, conv2_b, inputs, out, N);
}

// Round 8
// 1720.895 us; speedup vs baseline: 1.3737x; 1.3737x over previous
//
#include <hip/hip_runtime.h>
#include <hip/hip_bf16.h>

#define N_NODES 50000
#define N_EDGES 600000
#define CH 128
#define N_LAYERS 15
#define GB 391                      // gemm grid: 128-row tiles

typedef float f32x4 __attribute__((ext_vector_type(4)));
typedef short s16x8 __attribute__((ext_vector_type(8)));
typedef unsigned short u16x4 __attribute__((ext_vector_type(4)));

#define LD8(p) (*(const s16x8*)(p))

__device__ __forceinline__ float eluf(float v) {
    return v > 0.f ? v : (__expf(v) - 1.f);
}
__device__ __forceinline__ unsigned short f2bf(float f) {
    unsigned int u = __float_as_uint(f);
    unsigned int r = (u + 0x7FFFu + ((u >> 16) & 1u)) >> 16;
    return (unsigned short)r;
}
__device__ __forceinline__ float bf2f(unsigned short h) {
    return __uint_as_float(((unsigned int)h) << 16);
}
__device__ __forceinline__ void gload_lds16(const unsigned short* g, unsigned short* l) {
    __builtin_amdgcn_global_load_lds(
        (const __attribute__((address_space(1))) unsigned int*)g,
        (__attribute__((address_space(3))) unsigned int*)l, 16, 0, 0);
}

// ---------------- conv1 ----------------
__global__ __launch_bounds__(256) void conv1_kernel(
    const float* __restrict__ in, const float* __restrict__ W1,
    const float* __restrict__ b1, float* __restrict__ x,
    unsigned short* __restrict__ hbh, unsigned short* __restrict__ hbl, int n)
{
    int idx = blockIdx.x * blockDim.x + threadIdx.x;
    if (idx >= n * CH) return;
    int node = idx >> 7;
    int c = idx & 127;
    float o = b1[c]
            + in[(size_t)node * 3 + 0] * W1[0 * CH + c]
            + in[(size_t)node * 3 + 1] * W1[1 * CH + c]
            + in[(size_t)node * 3 + 2] * W1[2 * CH + c];
    x[idx] = o;
    float e = eluf(o);
    unsigned short hi = f2bf(e);
    hbh[idx] = hi;
    hbl[idx] = f2bf(e - bf2f(hi));
}

// ---------------- zero helpers ----------------
__global__ __launch_bounds__(256) void zero_int_kernel(int* __restrict__ p, int n) {
    int i = blockIdx.x * blockDim.x + threadIdx.x;
    if (i < n) p[i] = 0;
}
__global__ __launch_bounds__(256) void zero_float_kernel(float* __restrict__ p, int n) {
    int i = blockIdx.x * blockDim.x + threadIdx.x;
    if (i < n) p[i] = 0.f;
}

// ---------------- CSR build ----------------
__global__ __launch_bounds__(256) void count_kernel(
    const int* __restrict__ row, int* __restrict__ cnt, int e)
{
    int i = blockIdx.x * blockDim.x + threadIdx.x;
    if (i < e) atomicAdd(&cnt[row[i]], 1);
}

__global__ __launch_bounds__(1024) void block_reduce_kernel(
    const int* __restrict__ cnt, int* __restrict__ bsum, int n)
{
    __shared__ int sd[1024];
    int tid = threadIdx.x;
    int i = blockIdx.x * 1024 + tid;
    sd[tid] = (i < n) ? cnt[i] : 0;
    __syncthreads();
    for (int off = 512; off > 0; off >>= 1) {
        if (tid < off) sd[tid] += sd[tid + off];
        __syncthreads();
    }
    if (tid == 0) bsum[blockIdx.x] = sd[0];
}

__global__ __launch_bounds__(64) void scan_small_kernel(
    const int* __restrict__ bsum, int* __restrict__ boff, int nb)
{
    int lane = threadIdx.x;
    int orig = (lane < nb) ? bsum[lane] : 0;
    int v = orig;
#pragma unroll
    for (int d = 1; d < 64; d <<= 1) {
        int t = __shfl_up(v, d, 64);
        if (lane >= d) v += t;
    }
    if (lane < nb) boff[lane] = v - orig;  // exclusive
}

__global__ __launch_bounds__(1024) void block_scan_kernel(
    const int* __restrict__ cnt, const int* __restrict__ boff,
    int* __restrict__ row_ptr, int n)
{
    __shared__ int sd[1024];
    int tid = threadIdx.x;
    int i = blockIdx.x * 1024 + tid;
    sd[tid] = (i < n) ? cnt[i] : 0;
    __syncthreads();
    for (int off = 1; off < 1024; off <<= 1) {
        int t = (tid >= off) ? sd[tid - off] : 0;
        __syncthreads();
        sd[tid] += t;
        __syncthreads();
    }
    if (i < n) row_ptr[i + 1] = sd[tid] + boff[blockIdx.x];
    if (i == 0) row_ptr[0] = 0;
}

// col_s stores byte offset of the gather row start: col << 8
__global__ __launch_bounds__(256) void fill_kernel(
    const int* __restrict__ row, const int* __restrict__ col,
    const float* __restrict__ val, int* __restrict__ cursor,
    const int* __restrict__ row_ptr, int* __restrict__ col_s,
    float* __restrict__ val_s, int e)
{
    int i = blockIdx.x * blockDim.x + threadIdx.x;
    if (i >= e) return;
    int r = row[i];
    int pos = atomicAdd(&cursor[r], 1);
    int dst = row_ptr[r] + pos;
    col_s[dst] = col[i] << 8;
    val_s[dst] = val[i];
}

// ---------------- mask denominator ----------------
__global__ __launch_bounds__(256) void mask_sum_kernel(
    const float* __restrict__ mask, float* __restrict__ denom, int n)
{
    __shared__ float sd[256];
    int tid = threadIdx.x;
    float s = 0.f;
    for (int i = blockIdx.x * 256 + tid; i < n; i += gridDim.x * 256) s += mask[i];
    sd[tid] = s;
    __syncthreads();
    for (int off = 128; off > 0; off >>= 1) {
        if (tid < off) sd[tid] += sd[tid + off];
        __syncthreads();
    }
    if (tid == 0) atomicAdd(denom, sd[0]);
}

// ---- W pre-split into MFMA-fragment order (hi + lo planes) ----
__global__ __launch_bounds__(256) void split_w_kernel(
    const float* __restrict__ W, unsigned short* __restrict__ Wf, int total)
{
    int id = blockIdx.x * 256 + threadIdx.x;
    if (id >= total) return;
    int s = id >> 15;
    int rem = id & 32767;
    int k = rem >> 7;
    int nn = rem & 127;
    float a = W[id];
    unsigned short hi = f2bf(a);
    float r = a - bf2f(hi);
    unsigned short mi = f2bf(r);
    int c   = k >> 5;
    int kin = k & 31;
    int q   = kin >> 3;
    int ko  = kin & 7;
    int nt  = nn >> 4;
    int c16 = nn & 15;
    int lane = q * 16 + c16;
    size_t base = (size_t)s * 65536 + (size_t)c * 4096 + (size_t)nt * 512
                + (size_t)lane * 8 + ko;
    Wf[base]         = hi;
    Wf[base + 32768] = mi;
}

// ======== shared GEMM building blocks (LDS slot-swizzle, rule 21) ========
__device__ __forceinline__ void dense4(
    const unsigned short* r0, const unsigned short* r1,
    const unsigned short* wf0, f32x4 (&acc)[2][4],
    s16x8 (&b0)[4], s16x8 (&b1)[4],
    int lrA, int lrB, int q, int xr, bool pf_last)
{
#pragma unroll
    for (int ch = 0; ch < 4; ++ch) {
        s16x8 nb0[4], nb1[4];
        const bool pf = (ch < 3) || pf_last;
        if (pf) {
            const unsigned short* nwp = wf0 + (size_t)(ch + 1) * 4096;
#pragma unroll
            for (int nt = 0; nt < 4; ++nt) {
                nb0[nt] = LD8(nwp + nt * 512);
                nb1[nt] = LD8(nwp + nt * 512 + 32768);
            }
        }
        const int sl = (((ch * 4 + q) ^ xr) << 3);
        s16x8 aH0 = LD8(r0 + lrA * 128 + sl);
        s16x8 aH1 = LD8(r0 + lrB * 128 + sl);
        s16x8 aL0 = LD8(r1 + lrA * 128 + sl);
        s16x8 aL1 = LD8(r1 + lrB * 128 + sl);
#pragma unroll
        for (int nt = 0; nt < 4; ++nt) {
            f32x4 c0 = acc[0][nt];
            c0 = __builtin_amdgcn_mfma_f32_16x16x32_bf16(aH0, b0[nt], c0, 0, 0, 0);
            c0 = __builtin_amdgcn_mfma_f32_16x16x32_bf16(aH0, b1[nt], c0, 0, 0, 0);
            c0 = __builtin_amdgcn_mfma_f32_16x16x32_bf16(aL0, b0[nt], c0, 0, 0, 0);
            acc[0][nt] = c0;
            f32x4 c1 = acc[1][nt];
            c1 = __builtin_amdgcn_mfma_f32_16x16x32_bf16(aH1, b0[nt], c1, 0, 0, 0);
            c1 = __builtin_amdgcn_mfma_f32_16x16x32_bf16(aH1, b1[nt], c1, 0, 0, 0);
            c1 = __builtin_amdgcn_mfma_f32_16x16x32_bf16(aL1, b0[nt], c1, 0, 0, 0);
            acc[1][nt] = c1;
        }
        if (pf) {
#pragma unroll
            for (int nt = 0; nt < 4; ++nt) { b0[nt] = nb0[nt]; b1[nt] = nb1[nt]; }
        }
    }
}

__device__ __forceinline__ void prop4(
    const unsigned short* r1, const unsigned short* wf0, f32x4 (&acc)[2][4],
    s16x8 (&b0)[4], s16x8 (&b1)[4], int lrA, int lrB, int q, int xr)
{
#pragma unroll
    for (int cc = 0; cc < 4; ++cc) {
        s16x8 nb0[4], nb1[4];
        if (cc < 3) {
            const unsigned short* nwp = wf0 + (size_t)(5 + cc) * 4096;
#pragma unroll
            for (int nt = 0; nt < 4; ++nt) {
                nb0[nt] = LD8(nwp + nt * 512);
                nb1[nt] = LD8(nwp + nt * 512 + 32768);
            }
        }
        const int sl = (((cc * 4 + q) ^ xr) << 3);
        s16x8 p0 = LD8(r1 + lrA * 128 + sl);
        s16x8 p1 = LD8(r1 + lrB * 128 + sl);
#pragma unroll
        for (int nt = 0; nt < 4; ++nt) {
            f32x4 c0 = acc[0][nt];
            c0 = __builtin_amdgcn_mfma_f32_16x16x32_bf16(p0, b0[nt], c0, 0, 0, 0);
            c0 = __builtin_amdgcn_mfma_f32_16x16x32_bf16(p0, b1[nt], c0, 0, 0, 0);
            acc[0][nt] = c0;
            f32x4 c1 = acc[1][nt];
            c1 = __builtin_amdgcn_mfma_f32_16x16x32_bf16(p1, b0[nt], c1, 0, 0, 0);
            c1 = __builtin_amdgcn_mfma_f32_16x16x32_bf16(p1, b1[nt], c1, 0, 0, 0);
            acc[1][nt] = c1;
        }
        if (cc < 3) {
#pragma unroll
            for (int nt = 0; nt < 4; ++nt) { b0[nt] = nb0[nt]; b1[nt] = nb1[nt]; }
        }
    }
}

// ---------------- fused GEMM: 128-row tile, 8 waves, 391 blocks.
// B-L2 traffic halves vs 64-row tiles (waves sharing wn dedup B in L1/L2;
// unique B per block = 256KB per 128 rows instead of per 64). For LAP steps
// the Laplacian gather runs in-kernel (input = prev dispatch's planes ->
// dispatch-boundary visibility, no fences), writing prop into the dead lo
// region; prop never touches global. Epilogue fp32 tile overlays everything.
// LDS ~73KB -> 2 blocks/CU -> all 391 co-resident, 16 waves/CU.
template<bool LAP>
__global__ __launch_bounds__(512, 4) void gemm_fused_kernel(
    const unsigned short* __restrict__ Ah, const unsigned short* __restrict__ Al,
    const unsigned short* __restrict__ Wf, const float* __restrict__ bias,
    const float* __restrict__ res, float* __restrict__ out,
    unsigned short* __restrict__ Oh, unsigned short* __restrict__ Ol,
    const float* __restrict__ mask, float* __restrict__ accp,
    const float* __restrict__ accv, const float* __restrict__ Wb,
    const float* __restrict__ denom,
    const int* __restrict__ rp, const int* __restrict__ cols,
    const float* __restrict__ vals, int n)
{
    __shared__ __align__(16) char smem[69632];     // [hi 32K][lo 32K][pad]; tile overlay 67.6K
    __shared__ float csum[128];
    __shared__ float partial[512];
    __shared__ float bias_s[128];
    unsigned short* r0 = (unsigned short*)smem;
    unsigned short* r1 = (unsigned short*)(smem + 32768);
    float* tile = (float*)smem;

    const int tid = threadIdx.x;
    const int m_base = blockIdx.x * 128;
    const int wid = tid >> 6, lane = tid & 63;
    const int wm = wid & 3, wn = wid >> 2;         // row quarter / col half
    const int q = lane >> 4, c16 = lane & 15;
    const int lrA = wm * 32 + c16, lrB = lrA + 16;
    const int xr = lrA & 7;

    // ---- stage hi->r0, lo->r1 (swizzled source, linear LDS dest) ----
    {
        const int lr = tid >> 4, slot = tid & 15;
#pragma unroll
        for (int k = 0; k < 4; ++k) {
            int row = k * 32 + lr;
            int ss = (slot ^ (row & 7)) * 8;
            size_t g = (size_t)(m_base + row) * CH + ss;
            gload_lds16(Ah + g, r0 + k * 4096 + tid * 8);
            gload_lds16(Al + g, r1 + k * 4096 + tid * 8);
        }
    }
    if (tid < 128) bias_s[tid] = bias[tid];
    if (!LAP) {   // avg-step bias2 GEMV from prev-dispatch acc slot
        float rden = 1.f / denom[0];
        int c = tid & 127, h = tid >> 7;           // h in 0..3, 32 k's each
        float o = 0.f;
#pragma unroll 8
        for (int k = h * 32; k < h * 32 + 32; ++k) o += accv[k] * Wb[(size_t)k * CH + c];
        partial[tid] = o * rden;
    }

    f32x4 acc[2][4];
#pragma unroll
    for (int a = 0; a < 2; a++)
#pragma unroll
        for (int b = 0; b < 4; b++) acc[a][b] = (f32x4){0.f, 0.f, 0.f, 0.f};

    const unsigned short* wf0 = Wf + wn * 2048 + lane * 8;
    s16x8 b0[4], b1[4];
#pragma unroll
    for (int nt = 0; nt < 4; ++nt) {
        b0[nt] = LD8(wf0 + nt * 512);
        b1[nt] = LD8(wf0 + nt * 512 + 32768);
    }
    __syncthreads();                   // staging drained; bias/partial visible
    if (!LAP && tid < 128)
        bias_s[tid] += partial[tid] + partial[tid + 128]
                     + partial[tid + 256] + partial[tid + 384];

    dense4(r0, r1, wf0, acc, b0, b1, lrA, lrB, q, xr, LAP);

    if (LAP) {
        __syncthreads();               // lo reads done -> r1 reusable
        // ---- in-kernel gather: own 128 rows over ALL-rows Ah -> r1 (prop) ----
        {
            const char* hbase = (const char*)Ah;
            const int gw = tid >> 6, gl = tid & 63;
            for (int rr = 0; rr < 16; ++rr) {
                int lrow = gw * 16 + rr;
                int grow = m_base + lrow;
                float a0 = 0.f, a1 = 0.f;
                if (grow < n) {
                    int st = rp[grow], en = rp[grow + 1];
                    int t = st;
                    for (; t + 4 <= en; t += 4) {
                        int e0 = cols[t], e1 = cols[t + 1];
                        int e2 = cols[t + 2], e3 = cols[t + 3];
                        float v0 = vals[t], v1 = vals[t + 1];
                        float v2 = vals[t + 2], v3 = vals[t + 3];
                        unsigned int u0 = *(const unsigned int*)(hbase + e0 + gl * 4);
                        unsigned int u1 = *(const unsigned int*)(hbase + e1 + gl * 4);
                        unsigned int u2 = *(const unsigned int*)(hbase + e2 + gl * 4);
                        unsigned int u3 = *(const unsigned int*)(hbase + e3 + gl * 4);
                        a0 += v0 * bf2f((unsigned short)u0) + v1 * bf2f((unsigned short)u1)
                            + v2 * bf2f((unsigned short)u2) + v3 * bf2f((unsigned short)u3);
                        a1 += v0 * bf2f((unsigned short)(u0 >> 16)) + v1 * bf2f((unsigned short)(u1 >> 16))
                            + v2 * bf2f((unsigned short)(u2 >> 16)) + v3 * bf2f((unsigned short)(u3 >> 16));
                    }
                    for (; t < en; ++t) {
                        unsigned int u = *(const unsigned int*)(hbase + cols[t] + gl * 4);
                        float v = vals[t];
                        a0 += v * bf2f((unsigned short)u);
                        a1 += v * bf2f((unsigned short)(u >> 16));
                    }
                }
                int sw = (gl >> 2) ^ (lrow & 7);
                *(unsigned int*)((char*)r1 + lrow * 256 + sw * 16 + (gl & 3) * 4)
                    = (unsigned int)f2bf(a0) | ((unsigned int)f2bf(a1) << 16);
            }
        }
        __syncthreads();               // prop plane ready
        prop4(r1, wf0, acc, b0, b1, lrA, lrB, q, xr);
    }

    // ---- epilogue: tile overlays r0+r1 ----
    if (accp && tid < 128) csum[tid] = 0.f;
    __syncthreads();
#pragma unroll
    for (int mt = 0; mt < 2; ++mt)
#pragma unroll
        for (int nt = 0; nt < 4; ++nt) {
            int col = wn * 64 + nt * 16 + c16;
            float bv = bias_s[col];
            int lrow = wm * 32 + mt * 16 + q * 4;
#pragma unroll
            for (int r = 0; r < 4; ++r)
                tile[(lrow + r) * 132 + col] = acc[mt][nt][r] + bv;
        }
    __syncthreads();

    float colsum[4] = {0.f, 0.f, 0.f, 0.f};
    const int c4 = (tid & 31) << 2;
    for (int e4 = tid; e4 < 4096; e4 += 512) {
        int row = e4 >> 5;
        int grow = m_base + row;
        if (grow < n) {
            f32x4 v = *(const f32x4*)&tile[row * 132 + c4];
            size_t o4 = (size_t)grow * CH + c4;
            if (res) v = v + *(const f32x4*)(res + o4);
            if (out) *(f32x4*)(out + o4) = v;
            float e0 = eluf(v[0]), e1 = eluf(v[1]), e2 = eluf(v[2]), e3 = eluf(v[3]);
            unsigned short h0 = f2bf(e0), h1 = f2bf(e1), h2 = f2bf(e2), h3 = f2bf(e3);
            u16x4 hv = {h0, h1, h2, h3};
            u16x4 lv = {f2bf(e0 - bf2f(h0)), f2bf(e1 - bf2f(h1)),
                        f2bf(e2 - bf2f(h2)), f2bf(e3 - bf2f(h3))};
            *(u16x4*)(Oh + o4) = hv;
            *(u16x4*)(Ol + o4) = lv;
            if (accp) {
                float mk = mask[grow];
                colsum[0] += mk * e0; colsum[1] += mk * e1;
                colsum[2] += mk * e2; colsum[3] += mk * e3;
            }
        }
    }
    if (accp) {
#pragma unroll
        for (int jj = 0; jj < 4; ++jj) atomicAdd(&csum[c4 + jj], colsum[jj]);
        __syncthreads();
        if (tid < 128) atomicAdd(&accp[tid], csum[tid]);
    }
}

// ---------------- final head ----------------
__global__ __launch_bounds__(256) void final_kernel(
    const unsigned short* __restrict__ hh, const unsigned short* __restrict__ hl,
    const float* __restrict__ W2, const float* __restrict__ b2,
    const float* __restrict__ in, float* __restrict__ out, int n)
{
    int wave = (blockIdx.x * blockDim.x + threadIdx.x) >> 6;
    int lane = threadIdx.x & 63;
    int stride = gridDim.x * 4;
    for (int row = wave; row < n; row += stride) {
        size_t i1 = (size_t)row * CH + lane;
        size_t i2 = i1 + 64;
        float v = (bf2f(hh[i1]) + bf2f(hl[i1])) * W2[lane]
                + (bf2f(hh[i2]) + bf2f(hl[i2])) * W2[64 + lane];
#pragma unroll
        for (int off = 32; off > 0; off >>= 1) v += __shfl_down(v, off, 64);
        if (lane == 0) out[row] = v + b2[0] + in[(size_t)row * 3];
    }
}

extern "C" void kernel_launch(void* const* d_in, const int* in_sizes, int n_in,
                              void* d_out, int out_size, void* d_ws, size_t ws_size,
                              hipStream_t stream)
{
    const int*   L_row   = (const int*)d_in[0];
    const int*   L_col   = (const int*)d_in[1];
    const float* L_val   = (const float*)d_in[2];
    const float* mask    = (const float*)d_in[3];
    const float* inputs  = (const float*)d_in[4];
    const float* conv1_W = (const float*)d_in[5];
    const float* conv1_b = (const float*)d_in[6];
    const float* blocks_W = (const float*)d_in[7];
    const float* blocks_b = (const float*)d_in[8];
    const float* conv2_W = (const float*)d_in[9];
    const float* conv2_b = (const float*)d_in[10];
    float* out = (float*)d_out;

    const int N = N_NODES, E = N_EDGES;
    const size_t NF = (size_t)N * CH;
    const int NPAD = 50048;
    const int NB = (N + 1023) / 1024;

    float* ws = (float*)d_ws;
    float* x0 = ws;
    float* x1 = x0 + NF;
    unsigned short* hbh0 = (unsigned short*)(x1 + NF);
    unsigned short* hbl0 = hbh0 + NF;
    unsigned short* hbh1 = hbl0 + NF;
    unsigned short* hbl1 = hbh1 + NF;
    unsigned short* ph   = hbl1 + NF;                   // slack region (OOB tile reads)
    int* cnt     = (int*)(ph + 2 * NF);
    int* cursor  = cnt + NPAD;
    int* row_ptr = cursor + NPAD;
    int* bsum    = row_ptr + NPAD;
    int* boff    = bsum + 64;
    int* col_s   = boff + 64;
    float* val_s = (float*)(col_s + E);
    float* acc_base = val_s + E;                        // 14 slots x 128
    float* denom    = acc_base + 14 * CH;
    unsigned short* wt = (unsigned short*)(denom + 16 + 160);

    zero_int_kernel<<<(2 * NPAD + 255) / 256, 256, 0, stream>>>(cnt, 2 * NPAD);
    zero_float_kernel<<<(14 * CH + 16 + 255) / 256, 256, 0, stream>>>(acc_base, 14 * CH + 16);
    count_kernel<<<(E + 255) / 256, 256, 0, stream>>>(L_row, cnt, E);
    block_reduce_kernel<<<NB, 1024, 0, stream>>>(cnt, bsum, N);
    scan_small_kernel<<<1, 64, 0, stream>>>(bsum, boff, NB);
    block_scan_kernel<<<NB, 1024, 0, stream>>>(cnt, boff, row_ptr, N);
    fill_kernel<<<(E + 255) / 256, 256, 0, stream>>>(L_row, L_col, L_val, cursor,
                                                     row_ptr, col_s, val_s, E);
    mask_sum_kernel<<<64, 256, 0, stream>>>(mask, denom, N);
    split_w_kernel<<<(30 * 32768 + 255) / 256, 256, 0, stream>>>(blocks_W, wt, 30 * 32768);

    conv1_kernel<<<(N * CH + 255) / 256, 256, 0, stream>>>(inputs, conv1_W, conv1_b,
                                                           x0, hbh0, hbl0, N);

    float* xin = x0;
    float* xout = x1;

    for (int i = 0; i < N_LAYERS; ++i) {
        int s0 = i * 2, s1 = s0 + 1;
        if ((i & 1) == 0) {
            // lap layer: gather fused into each gemm (prev-dispatch input)
            gemm_fused_kernel<true><<<GB, 512, 0, stream>>>(
                hbh0, hbl0, wt + (size_t)s0 * 65536, blocks_b + (size_t)s0 * CH,
                nullptr, nullptr, hbh1, hbl1, mask, nullptr,
                nullptr, nullptr, denom, row_ptr, col_s, val_s, N);
            float* accp1 = (i < 14) ? acc_base + (size_t)i * CH : nullptr;
            gemm_fused_kernel<true><<<GB, 512, 0, stream>>>(
                hbh1, hbl1, wt + (size_t)s1 * 65536, blocks_b + (size_t)s1 * CH,
                xin, xout, hbh0, hbl0, mask, accp1,
                nullptr, nullptr, denom, row_ptr, col_s, val_s, N);
        } else {
            // avg layer: two dispatches, bias2 in-kernel from acc slots
            gemm_fused_kernel<false><<<GB, 512, 0, stream>>>(
                hbh0, hbl0, wt + (size_t)s0 * 65536, blocks_b + (size_t)s0 * CH,
                nullptr, nullptr, hbh1, hbl1, mask, acc_base + (size_t)i * CH,
                acc_base + (size_t)(i - 1) * CH,
                blocks_W + (size_t)s0 * 256 * CH + 128 * CH,
                denom, row_ptr, col_s, val_s, N);
            gemm_fused_kernel<false><<<GB, 512, 0, stream>>>(
                hbh1, hbl1, wt + (size_t)s1 * 65536, blocks_b + (size_t)s1 * CH,
                xin, xout, hbh0, hbl0, mask, nullptr,
                acc_base + (size_t)i * CH,
                blocks_W + (size_t)s1 * 256 * CH + 128 * CH,
                denom, row_ptr, col_s, val_s, N);
        }
        float* t = xin; xin = xout; xout = t;
    }
    final_kernel<<<2048, 256, 0, stream>>>(hbh0, hbl0, conv2_W, conv2_b, inputs, out, N);
}

// Round 9
// 1582.637 us; speedup vs baseline: 1.4937x; 1.0874x over previous
//
#include <hip/hip_runtime.h>
#include <hip/hip_bf16.h>

#define N_NODES 50000
#define N_EDGES 600000
#define CH 128
#define N_LAYERS 15
#define GB 391                      // gemm grid: 128-row tiles
#define LAP_BLOCKS 2048

typedef float f32x4 __attribute__((ext_vector_type(4)));
typedef short s16x8 __attribute__((ext_vector_type(8)));
typedef unsigned short u16x4 __attribute__((ext_vector_type(4)));

#define LD8(p) (*(const s16x8*)(p))

__device__ __forceinline__ float eluf(float v) {
    return v > 0.f ? v : (__expf(v) - 1.f);
}
__device__ __forceinline__ unsigned short f2bf(float f) {
    unsigned int u = __float_as_uint(f);
    unsigned int r = (u + 0x7FFFu + ((u >> 16) & 1u)) >> 16;
    return (unsigned short)r;
}
__device__ __forceinline__ float bf2f(unsigned short h) {
    return __uint_as_float(((unsigned int)h) << 16);
}
__device__ __forceinline__ void gload_lds16(const unsigned short* g, unsigned short* l) {
    __builtin_amdgcn_global_load_lds(
        (const __attribute__((address_space(1))) unsigned int*)g,
        (__attribute__((address_space(3))) unsigned int*)l, 16, 0, 0);
}

// ---------------- conv1 ----------------
__global__ __launch_bounds__(256) void conv1_kernel(
    const float* __restrict__ in, const float* __restrict__ W1,
    const float* __restrict__ b1, float* __restrict__ x,
    unsigned short* __restrict__ hbh, unsigned short* __restrict__ hbl, int n)
{
    int idx = blockIdx.x * blockDim.x + threadIdx.x;
    if (idx >= n * CH) return;
    int node = idx >> 7;
    int c = idx & 127;
    float o = b1[c]
            + in[(size_t)node * 3 + 0] * W1[0 * CH + c]
            + in[(size_t)node * 3 + 1] * W1[1 * CH + c]
            + in[(size_t)node * 3 + 2] * W1[2 * CH + c];
    x[idx] = o;
    float e = eluf(o);
    unsigned short hi = f2bf(e);
    hbh[idx] = hi;
    hbl[idx] = f2bf(e - bf2f(hi));
}

// ---------------- zero helpers ----------------
__global__ __launch_bounds__(256) void zero_int_kernel(int* __restrict__ p, int n) {
    int i = blockIdx.x * blockDim.x + threadIdx.x;
    if (i < n) p[i] = 0;
}
__global__ __launch_bounds__(256) void zero_float_kernel(float* __restrict__ p, int n) {
    int i = blockIdx.x * blockDim.x + threadIdx.x;
    if (i < n) p[i] = 0.f;
}

// ---------------- CSR build ----------------
__global__ __launch_bounds__(256) void count_kernel(
    const int* __restrict__ row, int* __restrict__ cnt, int e)
{
    int i = blockIdx.x * blockDim.x + threadIdx.x;
    if (i < e) atomicAdd(&cnt[row[i]], 1);
}

__global__ __launch_bounds__(1024) void block_reduce_kernel(
    const int* __restrict__ cnt, int* __restrict__ bsum, int n)
{
    __shared__ int sd[1024];
    int tid = threadIdx.x;
    int i = blockIdx.x * 1024 + tid;
    sd[tid] = (i < n) ? cnt[i] : 0;
    __syncthreads();
    for (int off = 512; off > 0; off >>= 1) {
        if (tid < off) sd[tid] += sd[tid + off];
        __syncthreads();
    }
    if (tid == 0) bsum[blockIdx.x] = sd[0];
}

__global__ __launch_bounds__(64) void scan_small_kernel(
    const int* __restrict__ bsum, int* __restrict__ boff, int nb)
{
    int lane = threadIdx.x;
    int orig = (lane < nb) ? bsum[lane] : 0;
    int v = orig;
#pragma unroll
    for (int d = 1; d < 64; d <<= 1) {
        int t = __shfl_up(v, d, 64);
        if (lane >= d) v += t;
    }
    if (lane < nb) boff[lane] = v - orig;  // exclusive
}

__global__ __launch_bounds__(1024) void block_scan_kernel(
    const int* __restrict__ cnt, const int* __restrict__ boff,
    int* __restrict__ row_ptr, int n)
{
    __shared__ int sd[1024];
    int tid = threadIdx.x;
    int i = blockIdx.x * 1024 + tid;
    sd[tid] = (i < n) ? cnt[i] : 0;
    __syncthreads();
    for (int off = 1; off < 1024; off <<= 1) {
        int t = (tid >= off) ? sd[tid - off] : 0;
        __syncthreads();
        sd[tid] += t;
        __syncthreads();
    }
    if (i < n) row_ptr[i + 1] = sd[tid] + boff[blockIdx.x];
    if (i == 0) row_ptr[0] = 0;
}

// col_s stores byte offset of the gather row start: col << 8
__global__ __launch_bounds__(256) void fill_kernel(
    const int* __restrict__ row, const int* __restrict__ col,
    const float* __restrict__ val, int* __restrict__ cursor,
    const int* __restrict__ row_ptr, int* __restrict__ col_s,
    float* __restrict__ val_s, int e)
{
    int i = blockIdx.x * blockDim.x + threadIdx.x;
    if (i >= e) return;
    int r = row[i];
    int pos = atomicAdd(&cursor[r], 1);
    int dst = row_ptr[r] + pos;
    col_s[dst] = col[i] << 8;
    val_s[dst] = val[i];
}

// ---------------- mask denominator ----------------
__global__ __launch_bounds__(256) void mask_sum_kernel(
    const float* __restrict__ mask, float* __restrict__ denom, int n)
{
    __shared__ float sd[256];
    int tid = threadIdx.x;
    float s = 0.f;
    for (int i = blockIdx.x * 256 + tid; i < n; i += gridDim.x * 256) s += mask[i];
    sd[tid] = s;
    __syncthreads();
    for (int off = 128; off > 0; off >>= 1) {
        if (tid < off) sd[tid] += sd[tid + off];
        __syncthreads();
    }
    if (tid == 0) atomicAdd(denom, sd[0]);
}

// ---- W pre-split into MFMA-fragment order (hi + lo planes) ----
__global__ __launch_bounds__(256) void split_w_kernel(
    const float* __restrict__ W, unsigned short* __restrict__ Wf, int total)
{
    int id = blockIdx.x * 256 + threadIdx.x;
    if (id >= total) return;
    int s = id >> 15;
    int rem = id & 32767;
    int k = rem >> 7;
    int nn = rem & 127;
    float a = W[id];
    unsigned short hi = f2bf(a);
    float r = a - bf2f(hi);
    unsigned short mi = f2bf(r);
    int c   = k >> 5;
    int kin = k & 31;
    int q   = kin >> 3;
    int ko  = kin & 7;
    int nt  = nn >> 4;
    int c16 = nn & 15;
    int lane = q * 16 + c16;
    size_t base = (size_t)s * 65536 + (size_t)c * 4096 + (size_t)nt * 512
                + (size_t)lane * 8 + ko;
    Wf[base]         = hi;
    Wf[base + 32768] = mi;
}

// ---------------- Laplacian: prop[row,:] = sum_e val * hb[col,:]
// PERSISTENT 2048 blocks, 2 wave-units/row, 8-deep unroll (R5-validated,
// ~13us standalone — 2.4x faster than in-gemm fusion, R8 lesson).
__global__ __launch_bounds__(256) void lap_kernel(
    const int* __restrict__ rp, const int* __restrict__ cols,
    const float* __restrict__ vals, const unsigned short* __restrict__ hb,
    unsigned short* __restrict__ ph, int n)
{
    int unit = (blockIdx.x * 256 + threadIdx.x) >> 6;    // global wave id
    int lane = threadIdx.x & 63;
    int ch2 = ((((unit & 1) << 6) + lane) << 1);         // byte offset in gather row
    int stride = (LAP_BLOCKS * 4) >> 1;                  // 2 units/row
    const char* hbase = (const char*)hb;
    for (int row = unit >> 1; row < n; row += stride) {
        int s = rp[row], e = rp[row + 1];
        float acc = 0.f;
        int t = s;
        for (; t + 8 <= e; t += 8) {
            int c0 = cols[t],     c1 = cols[t + 1], c2 = cols[t + 2], c3 = cols[t + 3];
            int c4 = cols[t + 4], c5 = cols[t + 5], c6 = cols[t + 6], c7 = cols[t + 7];
            float v0 = vals[t],     v1 = vals[t + 1], v2 = vals[t + 2], v3 = vals[t + 3];
            float v4 = vals[t + 4], v5 = vals[t + 5], v6 = vals[t + 6], v7 = vals[t + 7];
            float h0 = bf2f(*(const unsigned short*)(hbase + c0 + ch2));
            float h1 = bf2f(*(const unsigned short*)(hbase + c1 + ch2));
            float h2 = bf2f(*(const unsigned short*)(hbase + c2 + ch2));
            float h3 = bf2f(*(const unsigned short*)(hbase + c3 + ch2));
            float h4 = bf2f(*(const unsigned short*)(hbase + c4 + ch2));
            float h5 = bf2f(*(const unsigned short*)(hbase + c5 + ch2));
            float h6 = bf2f(*(const unsigned short*)(hbase + c6 + ch2));
            float h7 = bf2f(*(const unsigned short*)(hbase + c7 + ch2));
            acc += v0 * h0 + v1 * h1 + v2 * h2 + v3 * h3
                 + v4 * h4 + v5 * h5 + v6 * h6 + v7 * h7;
        }
        for (; t + 4 <= e; t += 4) {
            int c0 = cols[t], c1 = cols[t + 1], c2 = cols[t + 2], c3 = cols[t + 3];
            float v0 = vals[t], v1 = vals[t + 1], v2 = vals[t + 2], v3 = vals[t + 3];
            float h0 = bf2f(*(const unsigned short*)(hbase + c0 + ch2));
            float h1 = bf2f(*(const unsigned short*)(hbase + c1 + ch2));
            float h2 = bf2f(*(const unsigned short*)(hbase + c2 + ch2));
            float h3 = bf2f(*(const unsigned short*)(hbase + c3 + ch2));
            acc += v0 * h0 + v1 * h1 + v2 * h2 + v3 * h3;
        }
        for (; t < e; ++t)
            acc += vals[t] * bf2f(*(const unsigned short*)(hbase + cols[t] + ch2));
        ph[row * CH + (ch2 >> 1)] = f2bf(acc);
    }
}

// ======== GEMM building blocks (LDS slot-swizzle, rule 21) ========
__device__ __forceinline__ void dense4(
    const unsigned short* r0, const unsigned short* r1,
    const unsigned short* wf0, f32x4 (&acc)[2][4],
    s16x8 (&b0)[4], s16x8 (&b1)[4],
    int lrA, int lrB, int q, int xr, bool pf_last)
{
#pragma unroll
    for (int ch = 0; ch < 4; ++ch) {
        s16x8 nb0[4], nb1[4];
        const bool pf = (ch < 3) || pf_last;
        if (pf) {
            const unsigned short* nwp = wf0 + (size_t)(ch + 1) * 4096;
#pragma unroll
            for (int nt = 0; nt < 4; ++nt) {
                nb0[nt] = LD8(nwp + nt * 512);
                nb1[nt] = LD8(nwp + nt * 512 + 32768);
            }
        }
        const int sl = (((ch * 4 + q) ^ xr) << 3);
        s16x8 aH0 = LD8(r0 + lrA * 128 + sl);
        s16x8 aH1 = LD8(r0 + lrB * 128 + sl);
        s16x8 aL0 = LD8(r1 + lrA * 128 + sl);
        s16x8 aL1 = LD8(r1 + lrB * 128 + sl);
#pragma unroll
        for (int nt = 0; nt < 4; ++nt) {
            f32x4 c0 = acc[0][nt];
            c0 = __builtin_amdgcn_mfma_f32_16x16x32_bf16(aH0, b0[nt], c0, 0, 0, 0);
            c0 = __builtin_amdgcn_mfma_f32_16x16x32_bf16(aH0, b1[nt], c0, 0, 0, 0);
            c0 = __builtin_amdgcn_mfma_f32_16x16x32_bf16(aL0, b0[nt], c0, 0, 0, 0);
            acc[0][nt] = c0;
            f32x4 c1 = acc[1][nt];
            c1 = __builtin_amdgcn_mfma_f32_16x16x32_bf16(aH1, b0[nt], c1, 0, 0, 0);
            c1 = __builtin_amdgcn_mfma_f32_16x16x32_bf16(aH1, b1[nt], c1, 0, 0, 0);
            c1 = __builtin_amdgcn_mfma_f32_16x16x32_bf16(aL1, b0[nt], c1, 0, 0, 0);
            acc[1][nt] = c1;
        }
        if (pf) {
#pragma unroll
            for (int nt = 0; nt < 4; ++nt) { b0[nt] = nb0[nt]; b1[nt] = nb1[nt]; }
        }
    }
}

// ---------------- GEMM: 128-row tile, 8 waves, 391 blocks (B-L2 halved —
// the validated R8 win). LAP variant reads prop A-fragments REG-DIRECT from
// ph (16B/lane coalesced, issued before the dense phase, pipelined one chunk
// ahead — R3-validated). hi+lo staged in LDS; epilogue tile overlays.
template<bool LAP>
__global__ __launch_bounds__(512, 4) void gemm_fused_kernel(
    const unsigned short* __restrict__ Ah, const unsigned short* __restrict__ Al,
    const unsigned short* __restrict__ Ph,
    const unsigned short* __restrict__ Wf, const float* __restrict__ bias,
    const float* __restrict__ res, float* __restrict__ out,
    unsigned short* __restrict__ Oh, unsigned short* __restrict__ Ol,
    const float* __restrict__ mask, float* __restrict__ accp,
    const float* __restrict__ accv, const float* __restrict__ Wb,
    const float* __restrict__ denom, int n)
{
    __shared__ __align__(16) char smem[69632];     // [hi 32K][lo 32K]; tile overlay 67.6K
    __shared__ float csum[128];
    __shared__ float partial[512];
    __shared__ float bias_s[128];
    unsigned short* r0 = (unsigned short*)smem;
    unsigned short* r1 = (unsigned short*)(smem + 32768);
    float* tile = (float*)smem;

    const int tid = threadIdx.x;
    const int m_base = blockIdx.x * 128;
    const int wid = tid >> 6, lane = tid & 63;
    const int wm = wid & 3, wn = wid >> 2;         // row quarter / col half
    const int q = lane >> 4, c16 = lane & 15;
    const int lrA = wm * 32 + c16, lrB = lrA + 16;
    const int xr = lrA & 7;

    // ---- stage hi->r0, lo->r1 (swizzled source, linear LDS dest) ----
    {
        const int lr = tid >> 4, slot = tid & 15;
#pragma unroll
        for (int k = 0; k < 4; ++k) {
            int row = k * 32 + lr;
            int ss = (slot ^ (row & 7)) * 8;
            size_t g = (size_t)(m_base + row) * CH + ss;
            gload_lds16(Ah + g, r0 + k * 4096 + tid * 8);
            gload_lds16(Al + g, r1 + k * 4096 + tid * 8);
        }
    }
    // prop chunk-0 fragments issued NOW -> in flight across the dense phase
    const int poff0 = (m_base + lrA) * CH + q * 8;
    const int poff1 = poff0 + 16 * CH;
    s16x8 pc0, pc1;
    if (LAP) { pc0 = LD8(Ph + poff0); pc1 = LD8(Ph + poff1); }

    if (tid < 128) bias_s[tid] = bias[tid];
    if (!LAP) {   // avg-step bias2 GEMV from prev-dispatch acc slot
        float rden = 1.f / denom[0];
        int c = tid & 127, h = tid >> 7;           // h in 0..3, 32 k's each
        float o = 0.f;
#pragma unroll 8
        for (int k = h * 32; k < h * 32 + 32; ++k) o += accv[k] * Wb[(size_t)k * CH + c];
        partial[tid] = o * rden;
    }

    f32x4 acc[2][4];
#pragma unroll
    for (int a = 0; a < 2; a++)
#pragma unroll
        for (int b = 0; b < 4; b++) acc[a][b] = (f32x4){0.f, 0.f, 0.f, 0.f};

    const unsigned short* wf0 = Wf + wn * 2048 + lane * 8;
    s16x8 b0[4], b1[4];
#pragma unroll
    for (int nt = 0; nt < 4; ++nt) {
        b0[nt] = LD8(wf0 + nt * 512);
        b1[nt] = LD8(wf0 + nt * 512 + 32768);
    }
    __syncthreads();                   // staging drained; bias/partial visible
    if (!LAP && tid < 128)
        bias_s[tid] += partial[tid] + partial[tid + 128]
                     + partial[tid + 256] + partial[tid + 384];

    dense4(r0, r1, wf0, acc, b0, b1, lrA, lrB, q, xr, LAP);

    if (LAP) {
        // ---- prop chunks 4..7: A reg-direct from ph, one chunk ahead ----
#pragma unroll
        for (int cc = 0; cc < 4; ++cc) {
            s16x8 np0, np1, nb0[4], nb1[4];
            if (cc < 3) {
                np0 = LD8(Ph + poff0 + (cc + 1) * 32);
                np1 = LD8(Ph + poff1 + (cc + 1) * 32);
                const unsigned short* nwp = wf0 + (size_t)(5 + cc) * 4096;
#pragma unroll
                for (int nt = 0; nt < 4; ++nt) {
                    nb0[nt] = LD8(nwp + nt * 512);
                    nb1[nt] = LD8(nwp + nt * 512 + 32768);
                }
            }
#pragma unroll
            for (int nt = 0; nt < 4; ++nt) {
                f32x4 c0 = acc[0][nt];
                c0 = __builtin_amdgcn_mfma_f32_16x16x32_bf16(pc0, b0[nt], c0, 0, 0, 0);
                c0 = __builtin_amdgcn_mfma_f32_16x16x32_bf16(pc0, b1[nt], c0, 0, 0, 0);
                acc[0][nt] = c0;
                f32x4 c1 = acc[1][nt];
                c1 = __builtin_amdgcn_mfma_f32_16x16x32_bf16(pc1, b0[nt], c1, 0, 0, 0);
                c1 = __builtin_amdgcn_mfma_f32_16x16x32_bf16(pc1, b1[nt], c1, 0, 0, 0);
                acc[1][nt] = c1;
            }
            if (cc < 3) {
                pc0 = np0; pc1 = np1;
#pragma unroll
                for (int nt = 0; nt < 4; ++nt) { b0[nt] = nb0[nt]; b1[nt] = nb1[nt]; }
            }
        }
    }

    // ---- epilogue: tile overlays r0+r1 ----
    if (accp && tid < 128) csum[tid] = 0.f;
    __syncthreads();
#pragma unroll
    for (int mt = 0; mt < 2; ++mt)
#pragma unroll
        for (int nt = 0; nt < 4; ++nt) {
            int col = wn * 64 + nt * 16 + c16;
            float bv = bias_s[col];
            int lrow = wm * 32 + mt * 16 + q * 4;
#pragma unroll
            for (int r = 0; r < 4; ++r)
                tile[(lrow + r) * 132 + col] = acc[mt][nt][r] + bv;
        }
    __syncthreads();

    float colsum[4] = {0.f, 0.f, 0.f, 0.f};
    const int c4 = (tid & 31) << 2;
    for (int e4 = tid; e4 < 4096; e4 += 512) {
        int row = e4 >> 5;
        int grow = m_base + row;
        if (grow < n) {
            f32x4 v = *(const f32x4*)&tile[row * 132 + c4];
            size_t o4 = (size_t)grow * CH + c4;
            if (res) v = v + *(const f32x4*)(res + o4);
            if (out) *(f32x4*)(out + o4) = v;
            float e0 = eluf(v[0]), e1 = eluf(v[1]), e2 = eluf(v[2]), e3 = eluf(v[3]);
            unsigned short h0 = f2bf(e0), h1 = f2bf(e1), h2 = f2bf(e2), h3 = f2bf(e3);
            u16x4 hv = {h0, h1, h2, h3};
            u16x4 lv = {f2bf(e0 - bf2f(h0)), f2bf(e1 - bf2f(h1)),
                        f2bf(e2 - bf2f(h2)), f2bf(e3 - bf2f(h3))};
            *(u16x4*)(Oh + o4) = hv;
            *(u16x4*)(Ol + o4) = lv;
            if (accp) {
                float mk = mask[grow];
                colsum[0] += mk * e0; colsum[1] += mk * e1;
                colsum[2] += mk * e2; colsum[3] += mk * e3;
            }
        }
    }
    if (accp) {
#pragma unroll
        for (int jj = 0; jj < 4; ++jj) atomicAdd(&csum[c4 + jj], colsum[jj]);
        __syncthreads();
        if (tid < 128) atomicAdd(&accp[tid], csum[tid]);
    }
}

// ---------------- final head ----------------
__global__ __launch_bounds__(256) void final_kernel(
    const unsigned short* __restrict__ hh, const unsigned short* __restrict__ hl,
    const float* __restrict__ W2, const float* __restrict__ b2,
    const float* __restrict__ in, float* __restrict__ out, int n)
{
    int wave = (blockIdx.x * blockDim.x + threadIdx.x) >> 6;
    int lane = threadIdx.x & 63;
    int stride = gridDim.x * 4;
    for (int row = wave; row < n; row += stride) {
        size_t i1 = (size_t)row * CH + lane;
        size_t i2 = i1 + 64;
        float v = (bf2f(hh[i1]) + bf2f(hl[i1])) * W2[lane]
                + (bf2f(hh[i2]) + bf2f(hl[i2])) * W2[64 + lane];
#pragma unroll
        for (int off = 32; off > 0; off >>= 1) v += __shfl_down(v, off, 64);
        if (lane == 0) out[row] = v + b2[0] + in[(size_t)row * 3];
    }
}

extern "C" void kernel_launch(void* const* d_in, const int* in_sizes, int n_in,
                              void* d_out, int out_size, void* d_ws, size_t ws_size,
                              hipStream_t stream)
{
    const int*   L_row   = (const int*)d_in[0];
    const int*   L_col   = (const int*)d_in[1];
    const float* L_val   = (const float*)d_in[2];
    const float* mask    = (const float*)d_in[3];
    const float* inputs  = (const float*)d_in[4];
    const float* conv1_W = (const float*)d_in[5];
    const float* conv1_b = (const float*)d_in[6];
    const float* blocks_W = (const float*)d_in[7];
    const float* blocks_b = (const float*)d_in[8];
    const float* conv2_W = (const float*)d_in[9];
    const float* conv2_b = (const float*)d_in[10];
    float* out = (float*)d_out;

    const int N = N_NODES, E = N_EDGES;
    const size_t NF = (size_t)N * CH;
    const int NPAD = 50048;
    const int NB = (N + 1023) / 1024;

    float* ws = (float*)d_ws;
    float* x0 = ws;
    float* x1 = x0 + NF;
    unsigned short* hbh0 = (unsigned short*)(x1 + NF);
    unsigned short* hbl0 = hbh0 + NF;
    unsigned short* hbh1 = hbl0 + NF;
    unsigned short* hbl1 = hbh1 + NF;
    unsigned short* ph   = hbl1 + NF;                   // prop hi plane (2*NF slack)
    int* cnt     = (int*)(ph + 2 * NF);
    int* cursor  = cnt + NPAD;
    int* row_ptr = cursor + NPAD;
    int* bsum    = row_ptr + NPAD;
    int* boff    = bsum + 64;
    int* col_s   = boff + 64;
    float* val_s = (float*)(col_s + E);
    float* acc_base = val_s + E;                        // 14 slots x 128
    float* denom    = acc_base + 14 * CH;
    unsigned short* wt = (unsigned short*)(denom + 16 + 160);

    zero_int_kernel<<<(2 * NPAD + 255) / 256, 256, 0, stream>>>(cnt, 2 * NPAD);
    zero_float_kernel<<<(14 * CH + 16 + 255) / 256, 256, 0, stream>>>(acc_base, 14 * CH + 16);
    count_kernel<<<(E + 255) / 256, 256, 0, stream>>>(L_row, cnt, E);
    block_reduce_kernel<<<NB, 1024, 0, stream>>>(cnt, bsum, N);
    scan_small_kernel<<<1, 64, 0, stream>>>(bsum, boff, NB);
    block_scan_kernel<<<NB, 1024, 0, stream>>>(cnt, boff, row_ptr, N);
    fill_kernel<<<(E + 255) / 256, 256, 0, stream>>>(L_row, L_col, L_val, cursor,
                                                     row_ptr, col_s, val_s, E);
    mask_sum_kernel<<<64, 256, 0, stream>>>(mask, denom, N);
    split_w_kernel<<<(30 * 32768 + 255) / 256, 256, 0, stream>>>(blocks_W, wt, 30 * 32768);

    conv1_kernel<<<(N * CH + 255) / 256, 256, 0, stream>>>(inputs, conv1_W, conv1_b,
                                                           x0, hbh0, hbl0, N);

    float* xin = x0;
    float* xout = x1;

    for (int i = 0; i < N_LAYERS; ++i) {
        int s0 = i * 2, s1 = s0 + 1;
        if ((i & 1) == 0) {
            // lap layer: dedicated lap kernel + 128-row gemm with ph reg-direct
            lap_kernel<<<LAP_BLOCKS, 256, 0, stream>>>(row_ptr, col_s, val_s, hbh0, ph, N);
            gemm_fused_kernel<true><<<GB, 512, 0, stream>>>(
                hbh0, hbl0, ph, wt + (size_t)s0 * 65536, blocks_b + (size_t)s0 * CH,
                nullptr, nullptr, hbh1, hbl1, mask, nullptr,
                nullptr, nullptr, denom, N);
            lap_kernel<<<LAP_BLOCKS, 256, 0, stream>>>(row_ptr, col_s, val_s, hbh1, ph, N);
            float* accp1 = (i < 14) ? acc_base + (size_t)i * CH : nullptr;
            gemm_fused_kernel<true><<<GB, 512, 0, stream>>>(
                hbh1, hbl1, ph, wt + (size_t)s1 * 65536, blocks_b + (size_t)s1 * CH,
                xin, xout, hbh0, hbl0, mask, accp1,
                nullptr, nullptr, denom, N);
        } else {
            // avg layer: two dispatches, bias2 in-kernel from acc slots
            gemm_fused_kernel<false><<<GB, 512, 0, stream>>>(
                hbh0, hbl0, nullptr, wt + (size_t)s0 * 65536, blocks_b + (size_t)s0 * CH,
                nullptr, nullptr, hbh1, hbl1, mask, acc_base + (size_t)i * CH,
                acc_base + (size_t)(i - 1) * CH,
                blocks_W + (size_t)s0 * 256 * CH + 128 * CH,
                denom, N);
            gemm_fused_kernel<false><<<GB, 512, 0, stream>>>(
                hbh1, hbl1, nullptr, wt + (size_t)s1 * 65536, blocks_b + (size_t)s1 * CH,
                xin, xout, hbh0, hbl0, mask, nullptr,
                acc_base + (size_t)i * CH,
                blocks_W + (size_t)s1 * 256 * CH + 128 * CH,
                denom, N);
        }
        float* t = xin; xin = xout; xout = t;
    }
    final_kernel<<<2048, 256, 0, stream>>>(hbh0, hbl0, conv2_W, conv2_b, inputs, out, N);
}